// Round 13
// baseline (884.933 us; speedup 1.0000x reference)
//
#include <hip/hip_runtime.h>
#include <cstdint>
#include <cstddef>

// Problem constants
#define SEQL   256
#define NBATCH 64
#define HDIM   512
#define ZDIM   2048   // 4*OUT
#define KDIM   1536   // in_dim

typedef __attribute__((ext_vector_type(8))) short short8;
typedef __attribute__((ext_vector_type(4))) float f32x4;
typedef __attribute__((ext_vector_type(2))) float f32x2;
typedef __attribute__((ext_vector_type(4))) float f4v;
typedef unsigned long long ull;

static __device__ __forceinline__ unsigned short f2bf(float f) {
  union { float f; unsigned u; } v; v.f = f;
  unsigned u = v.u;
  unsigned r = (u + 0x7FFFu + ((u >> 16) & 1u)) >> 16;   // RNE
  return (unsigned short)r;
}
static __device__ __forceinline__ float bf2f(unsigned short s) {
  union { unsigned u; float f; } v; v.u = ((unsigned)s) << 16; return v.f;
}
static __device__ __forceinline__ float sigm(float x)  { return 1.f / (1.f + __expf(-x)); }
static __device__ __forceinline__ float tanh_f(float x){ return 1.f - 2.f / (__expf(2.f * x) + 1.f); }

static __device__ __forceinline__ void gl_lds16(const void* g, void* l) {
  __builtin_amdgcn_global_load_lds((const __attribute__((address_space(1))) unsigned int*)g,
                                   (__attribute__((address_space(3))) unsigned int*)l, 16, 0, 0);
}

// ---------------------------------------------------------------- prep kernels

// x (b,t,k) f32 -> Xb[r][k] bf16 with r = t*64 + b
__global__ __launch_bounds__(256) void k_convx(const float* __restrict__ x,
                                               unsigned short* __restrict__ Xb) {
  int i = blockIdx.x * 256 + threadIdx.x;
  int k8 = (i & 63) * 8;
  int r  = i >> 6;
  int b  = r & 63, t = r >> 6;
  const float* src = x + ((size_t)(b * SEQL + t) * HDIM + k8);
  f4v v0 = *(const f4v*)src;
  f4v v1 = *(const f4v*)(src + 4);
  short8 o;
#pragma unroll
  for (int j = 0; j < 4; ++j) o[j] = (short)f2bf(v0[j]);
#pragma unroll
  for (int j = 0; j < 4; ++j) o[4 + j] = (short)f2bf(v1[j]);
  *(short8*)(Xb + (size_t)r * HDIM + k8) = o;
}

// g (64,512) f32 -> bf16
__global__ __launch_bounds__(256) void k_convg(const float* __restrict__ g,
                                               unsigned short* __restrict__ gbf) {
  int i = blockIdx.x * 256 + threadIdx.x;
  int k8 = (i & 63) * 8;
  int row = i >> 6;
  const float* src = g + ((size_t)row * HDIM + k8);
  f4v v0 = *(const f4v*)src;
  f4v v1 = *(const f4v*)(src + 4);
  short8 o;
#pragma unroll
  for (int j = 0; j < 4; ++j) o[j] = (short)f2bf(v0[j]);
#pragma unroll
  for (int j = 0; j < 4; ++j) o[4 + j] = (short)f2bf(v1[j]);
  *(short8*)(gbf + (size_t)row * HDIM + k8) = o;
}

// W (1536,2048) f32 -> Wt (2048,1536) bf16 (transposed)
__global__ __launch_bounds__(256) void k_trans(const float* __restrict__ W,
                                               unsigned short* __restrict__ Wt) {
  __shared__ float tile[32][33];
  int tx = threadIdx.x & 31, ty = threadIdx.x >> 5;
  int n0 = blockIdx.x * 32;
  int j0 = blockIdx.y * 32;
#pragma unroll
  for (int jj = 0; jj < 4; ++jj)
    tile[ty + jj * 8][tx] = W[(size_t)(j0 + ty + jj * 8) * ZDIM + n0 + tx];
  __syncthreads();
#pragma unroll
  for (int jj = 0; jj < 4; ++jj)
    Wt[(size_t)(n0 + ty + jj * 8) * KDIM + j0 + tx] = f2bf(tile[tx][ty + jj * 8]);
}

// gbuf[64][2048] = g @ Wg + bias
__global__ __launch_bounds__(256) void k_gb(const unsigned short* __restrict__ gbf,
                                            const unsigned short* __restrict__ Wt,
                                            const float* __restrict__ bias,
                                            float* __restrict__ gbuf) {
  int tid = threadIdx.x, l = tid & 63, w = tid >> 6;
  int n0 = blockIdx.x * 64 + w * 16;
  f32x4 acc[4] = {};
#pragma unroll
  for (int kb = 0; kb < 16; ++kb) {
    short8 bfr = *(const short8*)((const char*)Wt + (size_t)(n0 + (l & 15)) * 3072
                                  + 2048 + kb * 64 + (l >> 4) * 16);
#pragma unroll
    for (int mi = 0; mi < 4; ++mi) {
      short8 afr = *(const short8*)((const char*)gbf + (size_t)(mi * 16 + (l & 15)) * 1024
                                    + kb * 64 + (l >> 4) * 16);
      acc[mi] = __builtin_amdgcn_mfma_f32_16x16x32_bf16(afr, bfr, acc[mi], 0, 0, 0);
    }
  }
  int r0 = (l >> 4) * 4, cq = l & 15;
#pragma unroll
  for (int mi = 0; mi < 4; ++mi)
#pragma unroll
    for (int reg = 0; reg < 4; ++reg) {
      int row = mi * 16 + r0 + reg, col = n0 + cq;
      gbuf[(size_t)row * ZDIM + col] = acc[mi][reg] + bias[col];
    }
}

// ------------------------------------------------- phase-1 GEMM: zpre = Xb @ Wx^T + gbuf
__global__ __launch_bounds__(256, 2) void k_gemm_p1(const unsigned short* __restrict__ Xb,
                                                    const unsigned short* __restrict__ Wt,
                                                    const float* __restrict__ gbuf,
                                                    unsigned short* __restrict__ zpre) {
  __shared__ unsigned char sm[32768];
  int tm = blockIdx.x, tn = blockIdx.y;
  int tid = threadIdx.x, l = tid & 63, w = tid >> 6;
  int m0w = (w & 1) * 64, n0w = (w >> 1) * 64;
  f32x4 acc[4][4] = {};

  for (int k0 = 0; k0 < HDIM; k0 += 64) {
#pragma unroll
    for (int j = 0; j < 8; ++j) {
      int c = j * 4 + w;
      int lane_row = l >> 3;
      int kb = (l & 7) * 16;
      const char* gsrc;
      if (c < 16) {
        int row = c * 8 + lane_row;
        gsrc = (const char*)Xb + (size_t)(tm * 128 + row) * 1024 + k0 * 2 + kb;
      } else {
        int row = (c - 16) * 8 + lane_row;
        gsrc = (const char*)Wt + (size_t)(tn * 128 + row) * 3072 + k0 * 2 + kb;
      }
      gl_lds16(gsrc, (char*)sm + c * 1024);
    }
    __syncthreads();

#pragma unroll
    for (int kk = 0; kk < 64; kk += 32) {
      short8 af[4], bf[4];
#pragma unroll
      for (int mi = 0; mi < 4; ++mi)
        af[mi] = *(const short8*)((const char*)sm + (size_t)(m0w + mi * 16 + (l & 15)) * 128
                                  + (kk + (l >> 4) * 8) * 2);
#pragma unroll
      for (int ni = 0; ni < 4; ++ni)
        bf[ni] = *(const short8*)((const char*)sm + 16384 + (size_t)(n0w + ni * 16 + (l & 15)) * 128
                                  + (kk + (l >> 4) * 8) * 2);
#pragma unroll
      for (int mi = 0; mi < 4; ++mi)
#pragma unroll
        for (int ni = 0; ni < 4; ++ni)
          acc[mi][ni] = __builtin_amdgcn_mfma_f32_16x16x32_bf16(af[mi], bf[ni], acc[mi][ni], 0, 0, 0);
    }
    __syncthreads();
  }

  int r0 = (l >> 4) * 4, cq = l & 15;
#pragma unroll
  for (int mi = 0; mi < 4; ++mi)
#pragma unroll
    for (int ni = 0; ni < 4; ++ni) {
      int col = tn * 128 + n0w + ni * 16 + cq;
#pragma unroll
      for (int reg = 0; reg < 4; ++reg) {
        int row = tm * 128 + m0w + mi * 16 + r0 + reg;
        float v = acc[mi][ni][reg] + gbuf[(size_t)(row & 63) * ZDIM + col];
        zpre[(size_t)row * ZDIM + col] = f2bf(v);
      }
    }
}

// ---------------------------------------------------------- persistent recurrence
// 128 wgs = dir(2) x band(4; 16 rows) x colgroup(16; 32 h-cols). 4 waves.
// SYNC = R8 verbatim: relaxed SYSTEM-scope 8B atomic packets, stamp = step,
// two parity regions; serial poll with full drain per iteration (proven floor).
// NEW (R13): FUSED GATE MATH. Wave w computes ALL 4 gates for h-cols w*8..w*8+7
// by packing B-fragment cols as {gate i | gate f} in acc0 and {o | u} in acc1
// (C-col c -> gate c>>3, hcol w*8+(c&7)). Lanes l and l^8 hold complementary
// gate pairs for the same hcol -> 8 shfl_xor(.,8) replace the zbuf LDS handoff
// and its __syncthreads. One barrier per step (As tile). Packet format is now
// (2 rows x 1 col): {bf16 h[2p], h[2p+1] of col c; stamp}.

__global__ __launch_bounds__(256, 1) void k_rec(const unsigned short* __restrict__ Wt,
                                                const unsigned short* __restrict__ zpre,
                                                ull* __restrict__ hbuf8,   // [2][2][4][8 rowpair][512 col]
                                                float* __restrict__ out,
                                                float* __restrict__ hstate,
                                                float* __restrict__ cstate) {
  __shared__ short lwh[4 * 32 * 512];         // 128KB: [gate][col(32)][k(512)] bf16, XOR-swizzled
  __shared__ unsigned char As[16 * 1024];     // 16KB: A tile [row(16)][k(512)] bf16, XOR-swizzled

  const int tid = threadIdx.x, l = tid & 63, gi = tid >> 6;   // gi = wave (h-col octet)
  const int bid = blockIdx.x;
  const int cg = bid & 15, gid = bid >> 4, dir = gid >> 2, bg = gid & 3;
  const int hc0 = cg * 32;

  // stage Wh slice (gate gi, cols hc0..hc0+31) into LDS. Consumption is now
  // cross-gate; the first in-loop barrier (step 0) orders staging before any
  // MFMA use (first MFMA is step 1).
#pragma unroll
  for (int col = 0; col < 32; ++col) {
    int kbs = l * 16;
    int kbyte = kbs ^ ((col & 7) << 4);
    short8 v = *(const short8*)((const char*)Wt
                + (size_t)(gi * 512 + hc0 + col) * 3072 + 1024 + kbyte);
    *(short8*)((char*)lwh + gi * 32768 + col * 1024 + kbs) = v;
  }

  // thread geometry (gate math / publish): rows r0, r0+1; h-col hcf
  const bool hi8 = (l & 8) != 0;
  const int r0  = (l >> 4) * 4 + (hi8 ? 2 : 0);     // band-local row (even)
  const int p   = r0 >> 1;                          // row-pair index 0..7
  const int hcf = hc0 + gi * 8 + (l & 7);           // full h-col 0..511
  float cs0 = 0.f, cs1 = 0.f, hh0 = 0.f, hh1 = 0.f;

  // zpre prefetch for first step: zp[g*2+j] = zpre[t][r0+j][gate g col hcf]
  unsigned short zp[8];
  {
    int t0 = dir ? (SEQL - 1) : 0;
    const unsigned short* zb = zpre + ((size_t)t0 * 64 + bg * 16 + r0) * ZDIM + hcf;
#pragma unroll
    for (int g = 0; g < 4; ++g) { zp[g * 2] = zb[g * 512]; zp[g * 2 + 1] = zb[2048 + g * 512]; }
  }

  // consumer poll geometry: wave gi polls k-chunks kb = gi*4..gi*4+3;
  // lane covers rowpair rp = l>>3, cols kb*32 + (l&7)*4 .. +3.
  const int rp = l >> 3;
  const size_t pbase = ((size_t)(dir * 4 + bg) * 8 + rp) * 512 + (l & 7) * 4;

  for (int s = 0; s < SEQL; ++s) {
    int t = dir ? (SEQL - 1 - s) : s;
    f32x4 acc0 = {0.f, 0.f, 0.f, 0.f}, acc1 = {0.f, 0.f, 0.f, 0.f};

    if (s) {
      // ---- poll (R8 semantics: serial, full drain per iteration)
      const unsigned e = (unsigned)(s - 1);
      const ull* hb = hbuf8 + (size_t)((s - 1) & 1) * 32768;
      ull v[16];
      int gd = 0; bool ok;
      do {
#pragma unroll
        for (int kk = 0; kk < 4; ++kk)
#pragma unroll
          for (int j = 0; j < 4; ++j)
            v[kk * 4 + j] = __hip_atomic_load(hb + pbase + (size_t)(gi * 4 + kk) * 32 + j,
                                              __ATOMIC_RELAXED, __HIP_MEMORY_SCOPE_SYSTEM);
        ok = true;
#pragma unroll
        for (int i = 0; i < 16; ++i) ok = ok && ((unsigned)(v[i] >> 32) == e);
      } while (!__all(ok) && ++gd < (1 << 17));   // hang guard

      // ---- strip to As: pack row-qwords via v_perm, 2 x ds_write_b64 per chunk
#pragma unroll
      for (int kk = 0; kk < 4; ++kk) {
        int kb = gi * 4 + kk;
        unsigned d0 = (unsigned)v[kk * 4 + 0], d1 = (unsigned)v[kk * 4 + 1];
        unsigned d2 = (unsigned)v[kk * 4 + 2], d3 = (unsigned)v[kk * 4 + 3];
        unsigned lo0 = __builtin_amdgcn_perm(d1, d0, 0x05040100u);
        unsigned lo1 = __builtin_amdgcn_perm(d3, d2, 0x05040100u);
        unsigned hi0 = __builtin_amdgcn_perm(d1, d0, 0x07060302u);
        unsigned hi1 = __builtin_amdgcn_perm(d3, d2, 0x07060302u);
        int row0 = rp * 2, row1 = row0 + 1;
        int cb = kb * 64 + (l & 7) * 8;
        *(ull*)(As + ((row0 * 1024 + cb) ^ ((row0 & 7) << 4))) = (ull)lo0 | ((ull)lo1 << 32);
        *(ull*)(As + ((row1 * 1024 + cb) ^ ((row1 & 7) << 4))) = (ull)hi0 | ((ull)hi1 << 32);
      }
    }
    __syncthreads();   // As ready (s==0: orders Wh staging; accs stay 0)

    if (s) {
      const int gsel = (l >> 3) & 1;                 // MFMA-col c>=8 -> gate 1 (acc0) / 3 (acc1)
      const int colb = (gi * 8 + (l & 7)) * 1024;    // Wh col byte base
#pragma unroll
      for (int kb = 0; kb < 16; ++kb) {
        int arow = l & 15;
        int abyte = (arow * 1024 + kb * 64 + (l >> 4) * 16) ^ ((arow & 7) << 4);
        short8 a = *(const short8*)(As + abyte);
        int kbyte = (kb * 64 + (l >> 4) * 16) ^ ((l & 7) << 4);
        short8 b0 = *(const short8*)((const char*)lwh + gsel * 32768 + colb + kbyte);
        short8 b1 = *(const short8*)((const char*)lwh + (2 + gsel) * 32768 + colb + kbyte);
        acc0 = __builtin_amdgcn_mfma_f32_16x16x32_bf16(a, b0, acc0, 0, 0, 0);
        acc1 = __builtin_amdgcn_mfma_f32_16x16x32_bf16(a, b1, acc1, 0, 0, 0);
      }
    }

    // ---- fused gate math: exchange complementary gates with lane l^8
    float sa0[4], sa1[4];
#pragma unroll
    for (int k2 = 0; k2 < 4; ++k2) {
      sa0[k2] = __shfl_xor(acc0[k2], 8, 64);
      sa1[k2] = __shfl_xor(acc1[k2], 8, 64);
    }
    // j = 0 (row r0)
    {
      float zi_ = (hi8 ? sa0[2] : acc0[0]) + bf2f(zp[0]);
      float zf_ = (hi8 ? acc0[2] : sa0[0]) + bf2f(zp[2]);
      float zo_ = (hi8 ? sa1[2] : acc1[0]) + bf2f(zp[4]);
      float zu_ = (hi8 ? acc1[2] : sa1[0]) + bf2f(zp[6]);
      cs0 = sigm(zf_) * cs0 + sigm(zi_) * tanh_f(zu_);
      hh0 = sigm(zo_) * tanh_f(cs0);
    }
    // j = 1 (row r0+1)
    {
      float zi_ = (hi8 ? sa0[3] : acc0[1]) + bf2f(zp[1]);
      float zf_ = (hi8 ? acc0[3] : sa0[1]) + bf2f(zp[3]);
      float zo_ = (hi8 ? sa1[3] : acc1[1]) + bf2f(zp[5]);
      float zu_ = (hi8 ? acc1[3] : sa1[1]) + bf2f(zp[7]);
      cs1 = sigm(zf_) * cs1 + sigm(zi_) * tanh_f(zu_);
      hh1 = sigm(zo_) * tanh_f(cs1);
    }

    // publish h packet {rows r0, r0+1 of col hcf; stamp = s}
    {
      unsigned hd = (unsigned)f2bf(hh0) | ((unsigned)f2bf(hh1) << 16);
      ull pv = (ull)hd | ((ull)(unsigned)s << 32);
      size_t p_idx = ((size_t)(dir * 4 + bg) * 8 + p) * 512 + hcf;
      __hip_atomic_store(hbuf8 + (size_t)(s & 1) * 32768 + p_idx, pv,
                         __ATOMIC_RELAXED, __HIP_MEMORY_SCOPE_SYSTEM);
    }

    // off-critical-path: out stores + next zpre prefetch
    __builtin_nontemporal_store(hh0,
        out + ((size_t)(bg * 16 + r0) * SEQL + t) * 1024 + dir * 512 + hcf);
    __builtin_nontemporal_store(hh1,
        out + ((size_t)(bg * 16 + r0 + 1) * SEQL + t) * 1024 + dir * 512 + hcf);
    if (s + 1 < SEQL) {
      int tn = dir ? (SEQL - 2 - s) : (s + 1);
      const unsigned short* zb = zpre + ((size_t)tn * 64 + bg * 16 + r0) * ZDIM + hcf;
#pragma unroll
      for (int g = 0; g < 4; ++g) { zp[g * 2] = zb[g * 512]; zp[g * 2 + 1] = zb[2048 + g * 512]; }
    }
  }

  // final states (2 rows x 1 col per thread)
  {
    size_t st = (size_t)(bg * 16 + r0) * 1024 + dir * 512 + hcf;
    __builtin_nontemporal_store(hh0, hstate + st);
    __builtin_nontemporal_store(cs0, cstate + st);
    __builtin_nontemporal_store(hh1, hstate + st + 1024);
    __builtin_nontemporal_store(cs1, cstate + st + 1024);
  }
}

// ---------------------------------------------------------------------- launch

extern "C" void kernel_launch(void* const* d_in, const int* in_sizes, int n_in,
                              void* d_out, int out_size, void* d_ws, size_t ws_size,
                              hipStream_t stream) {
  const float* x    = (const float*)d_in[0];
  const float* g    = (const float*)d_in[1];
  const float* W    = (const float*)d_in[2];
  const float* bias = (const float*)d_in[3];
  float* out = (float*)d_out;
  float* hstate = out + (size_t)16777216;            // 64*256*1024
  float* cstate = out + (size_t)16842752;            // + 64*1024

  char* ws = (char*)d_ws;
  ull* hbuf8 = (ull*)(ws + 0);                                // 512KB: 2 regions x 32768 packets
  unsigned short* Xb   = (unsigned short*)(ws + 524288);      // 16MB
  unsigned short* Wt   = (unsigned short*)(ws + 17301504);    // 6MB
  unsigned short* gbf  = (unsigned short*)(ws + 23592960);    // 64KB
  float*          gbuf = (float*)(ws + 23658496);             // 512KB
  unsigned short* zpre = (unsigned short*)(ws + 24182784);    // 64MB

  // pre-stamp both h regions with 0xFF (matches no expected stamp; also cleans
  // previous replay's stamps -- harness doesn't re-poison ws between replays).
  hipMemsetAsync((void*)hbuf8, 0xFF, 524288, stream);

  k_convx<<<4096, 256, 0, stream>>>(x, Xb);
  k_convg<<<16, 256, 0, stream>>>(g, gbf);
  k_trans<<<dim3(64, 48), 256, 0, stream>>>(W, Wt);
  k_gb<<<32, 256, 0, stream>>>(gbf, Wt, bias, gbuf);
  k_gemm_p1<<<dim3(128, 16), 256, 0, stream>>>(Xb, Wt, gbuf, zpre);
  k_rec<<<128, 256, 0, stream>>>(Wt, zpre, hbuf8, out, hstate, cstate);
}

// Round 14
// 777.492 us; speedup vs baseline: 1.1382x; 1.1382x over previous
//
#include <hip/hip_runtime.h>
#include <cstdint>
#include <cstddef>

// Problem constants
#define SEQL   256
#define NBATCH 64
#define HDIM   512
#define ZDIM   2048   // 4*OUT
#define KDIM   1536   // in_dim

typedef __attribute__((ext_vector_type(8))) short short8;
typedef __attribute__((ext_vector_type(4))) float f32x4;
typedef __attribute__((ext_vector_type(2))) float f32x2;
typedef __attribute__((ext_vector_type(4))) float f4v;
typedef unsigned long long ull;

static __device__ __forceinline__ unsigned short f2bf(float f) {
  union { float f; unsigned u; } v; v.f = f;
  unsigned u = v.u;
  unsigned r = (u + 0x7FFFu + ((u >> 16) & 1u)) >> 16;   // RNE
  return (unsigned short)r;
}
static __device__ __forceinline__ float bf2f(unsigned short s) {
  union { unsigned u; float f; } v; v.u = ((unsigned)s) << 16; return v.f;
}
static __device__ __forceinline__ float sigm(float x)  { return 1.f / (1.f + __expf(-x)); }
static __device__ __forceinline__ float tanh_f(float x){ return 1.f - 2.f / (__expf(2.f * x) + 1.f); }

static __device__ __forceinline__ void gl_lds16(const void* g, void* l) {
  __builtin_amdgcn_global_load_lds((const __attribute__((address_space(1))) unsigned int*)g,
                                   (__attribute__((address_space(3))) unsigned int*)l, 16, 0, 0);
}

// -------------------------------------------------------- fused prep kernel
// blocks 0..4095: x (b,t,k) f32 -> Xb[r=t*64+b][k] bf16
// blocks 4096..4111: g f32 -> gbf bf16
// blocks 4112..7183: W (1536,2048) f32 -> Wt (2048,1536) bf16 transposed
__global__ __launch_bounds__(256) void k_prep(const float* __restrict__ x,
                                              const float* __restrict__ g,
                                              const float* __restrict__ W,
                                              unsigned short* __restrict__ Xb,
                                              unsigned short* __restrict__ gbf,
                                              unsigned short* __restrict__ Wt) {
  __shared__ float tile[32][33];
  const int b = blockIdx.x;
  if (b < 4096) {
    int i = b * 256 + threadIdx.x;
    int k8 = (i & 63) * 8;
    int r  = i >> 6;
    int bb = r & 63, t = r >> 6;
    const float* src = x + ((size_t)(bb * SEQL + t) * HDIM + k8);
    f4v v0 = *(const f4v*)src;
    f4v v1 = *(const f4v*)(src + 4);
    short8 o;
#pragma unroll
    for (int j = 0; j < 4; ++j) o[j] = (short)f2bf(v0[j]);
#pragma unroll
    for (int j = 0; j < 4; ++j) o[4 + j] = (short)f2bf(v1[j]);
    *(short8*)(Xb + (size_t)r * HDIM + k8) = o;
  } else if (b < 4112) {
    int i = (b - 4096) * 256 + threadIdx.x;
    int k8 = (i & 63) * 8;
    int row = i >> 6;
    const float* src = g + ((size_t)row * HDIM + k8);
    f4v v0 = *(const f4v*)src;
    f4v v1 = *(const f4v*)(src + 4);
    short8 o;
#pragma unroll
    for (int j = 0; j < 4; ++j) o[j] = (short)f2bf(v0[j]);
#pragma unroll
    for (int j = 0; j < 4; ++j) o[4 + j] = (short)f2bf(v1[j]);
    *(short8*)(gbf + (size_t)row * HDIM + k8) = o;
  } else {
    int idx = b - 4112;
    int tx = threadIdx.x & 31, ty = threadIdx.x >> 5;
    int n0 = (idx & 63) * 32;
    int j0 = (idx >> 6) * 32;
#pragma unroll
    for (int jj = 0; jj < 4; ++jj)
      tile[ty + jj * 8][tx] = W[(size_t)(j0 + ty + jj * 8) * ZDIM + n0 + tx];
    __syncthreads();
#pragma unroll
    for (int jj = 0; jj < 4; ++jj)
      Wt[(size_t)(n0 + ty + jj * 8) * KDIM + j0 + tx] = f2bf(tile[tx][ty + jj * 8]);
  }
}

// gbuf[64][2048] = g @ Wg + bias
__global__ __launch_bounds__(256) void k_gb(const unsigned short* __restrict__ gbf,
                                            const unsigned short* __restrict__ Wt,
                                            const float* __restrict__ bias,
                                            float* __restrict__ gbuf) {
  int tid = threadIdx.x, l = tid & 63, w = tid >> 6;
  int n0 = blockIdx.x * 64 + w * 16;
  f32x4 acc[4] = {};
#pragma unroll
  for (int kb = 0; kb < 16; ++kb) {
    short8 bfr = *(const short8*)((const char*)Wt + (size_t)(n0 + (l & 15)) * 3072
                                  + 2048 + kb * 64 + (l >> 4) * 16);
#pragma unroll
    for (int mi = 0; mi < 4; ++mi) {
      short8 afr = *(const short8*)((const char*)gbf + (size_t)(mi * 16 + (l & 15)) * 1024
                                    + kb * 64 + (l >> 4) * 16);
      acc[mi] = __builtin_amdgcn_mfma_f32_16x16x32_bf16(afr, bfr, acc[mi], 0, 0, 0);
    }
  }
  int r0 = (l >> 4) * 4, cq = l & 15;
#pragma unroll
  for (int mi = 0; mi < 4; ++mi)
#pragma unroll
    for (int reg = 0; reg < 4; ++reg) {
      int row = mi * 16 + r0 + reg, col = n0 + cq;
      gbuf[(size_t)row * ZDIM + col] = acc[mi][reg] + bias[col];
    }
}

// ------------------------------------------------- phase-1 GEMM: zpre = Xb @ Wx^T + gbuf
__global__ __launch_bounds__(256, 2) void k_gemm_p1(const unsigned short* __restrict__ Xb,
                                                    const unsigned short* __restrict__ Wt,
                                                    const float* __restrict__ gbuf,
                                                    unsigned short* __restrict__ zpre) {
  __shared__ unsigned char sm[32768];
  int tm = blockIdx.x, tn = blockIdx.y;
  int tid = threadIdx.x, l = tid & 63, w = tid >> 6;
  int m0w = (w & 1) * 64, n0w = (w >> 1) * 64;
  f32x4 acc[4][4] = {};

  for (int k0 = 0; k0 < HDIM; k0 += 64) {
#pragma unroll
    for (int j = 0; j < 8; ++j) {
      int c = j * 4 + w;
      int lane_row = l >> 3;
      int kb = (l & 7) * 16;
      const char* gsrc;
      if (c < 16) {
        int row = c * 8 + lane_row;
        gsrc = (const char*)Xb + (size_t)(tm * 128 + row) * 1024 + k0 * 2 + kb;
      } else {
        int row = (c - 16) * 8 + lane_row;
        gsrc = (const char*)Wt + (size_t)(tn * 128 + row) * 3072 + k0 * 2 + kb;
      }
      gl_lds16(gsrc, (char*)sm + c * 1024);
    }
    __syncthreads();

#pragma unroll
    for (int kk = 0; kk < 64; kk += 32) {
      short8 af[4], bf[4];
#pragma unroll
      for (int mi = 0; mi < 4; ++mi)
        af[mi] = *(const short8*)((const char*)sm + (size_t)(m0w + mi * 16 + (l & 15)) * 128
                                  + (kk + (l >> 4) * 8) * 2);
#pragma unroll
      for (int ni = 0; ni < 4; ++ni)
        bf[ni] = *(const short8*)((const char*)sm + 16384 + (size_t)(n0w + ni * 16 + (l & 15)) * 128
                                  + (kk + (l >> 4) * 8) * 2);
#pragma unroll
      for (int mi = 0; mi < 4; ++mi)
#pragma unroll
        for (int ni = 0; ni < 4; ++ni)
          acc[mi][ni] = __builtin_amdgcn_mfma_f32_16x16x32_bf16(af[mi], bf[ni], acc[mi][ni], 0, 0, 0);
    }
    __syncthreads();
  }

  int r0 = (l >> 4) * 4, cq = l & 15;
#pragma unroll
  for (int mi = 0; mi < 4; ++mi)
#pragma unroll
    for (int ni = 0; ni < 4; ++ni) {
      int col = tn * 128 + n0w + ni * 16 + cq;
#pragma unroll
      for (int reg = 0; reg < 4; ++reg) {
        int row = tm * 128 + m0w + mi * 16 + r0 + reg;
        float v = acc[mi][ni][reg] + gbuf[(size_t)(row & 63) * ZDIM + col];
        zpre[(size_t)row * ZDIM + col] = f2bf(v);
      }
    }
}

// ---------------------------------------------------------- persistent recurrence
// R8 VERBATIM (proven 720us floor). 128 wgs = dir(2) x band(4; 16 rows) x
// colgroup(16; 32 h-cols). 4 waves = 4 gates. SYNC: 8B atomic packets
// {u32 data = 2xbf16 exact, u32 stamp = step} via relaxed SYSTEM-scope
// (L2-bypassing) ops. Stamp-match = arrival: detect + fetch = ONE coherence-
// point round trip, no fences, no flags, no drains. Two regions by s&1;
// overwrite-safety by data dependency. Waves cooperatively stage A into LDS
// (each wave polls its own 4 k-chunks). Regions pre-stamped 0xFF each launch.

__global__ __launch_bounds__(256, 1) void k_rec(const unsigned short* __restrict__ Wt,
                                                const unsigned short* __restrict__ zpre,
                                                ull* __restrict__ hbuf8,   // [2][2][64][256] packets
                                                float* __restrict__ out,
                                                float* __restrict__ hstate,
                                                float* __restrict__ cstate) {
  __shared__ short lwh[4 * 32 * 512];         // 128KB: [gate][col(32)][k(512)] bf16, XOR-swizzled
  __shared__ unsigned char As[16 * 1024];     // 16KB: A tile [row(16)][k(512)] bf16, XOR-swizzled
  __shared__ float zbuf[4][16][33];           // 8.4KB (+1 pad col)

  const int tid = threadIdx.x, l = tid & 63, gi = tid >> 6;   // wave = gate (i,f,o,u)
  const int bid = blockIdx.x;
  const int cg = bid & 15, gid = bid >> 4, dir = gid >> 2, bg = gid & 3;
  const int hc0 = cg * 32;

  // stage Wh slice (gate gi, cols hc0..hc0+31) into LDS; per-wave private region.
#pragma unroll
  for (int col = 0; col < 32; ++col) {
    int kbs = l * 16;
    int kbyte = kbs ^ ((col & 7) << 4);
    short8 v = *(const short8*)((const char*)Wt
                + (size_t)(gi * 512 + hc0 + col) * 3072 + 1024 + kbyte);
    *(short8*)((char*)lwh + gi * 32768 + col * 1024 + kbs) = v;
  }

  const int r = tid >> 4, q = tid & 15;   // gate-math: row r (0..15), cols 2q, 2q+1
  float c0 = 0.f, c1 = 0.f, h0 = 0.f, h1 = 0.f;

  // prefetch zpre for first step (cached loads; L2 stays warm)
  int t = dir ? (SEQL - 1) : 0;
  unsigned zp[4];
  {
    const char* zb = (const char*)zpre
        + (((size_t)t * 64 + bg * 16 + r) * ZDIM + hc0 + 2 * q) * 2;
#pragma unroll
    for (int gg = 0; gg < 4; ++gg) zp[gg] = *(const unsigned*)(zb + gg * 1024);
  }

  // producer packet index: [dir*64 + bg*16 + r][cg*16 + q]
  const size_t p_idx = ((size_t)(dir * 64 + bg * 16 + r)) * 256 + cg * 16 + q;
  // consumer: wave gi polls k-chunks kb = gi*4..gi*4+3; lane handles
  // rows it*4 + (l>>4), col-pair (l&15) of each chunk.
  const int c_row = l >> 4, c_cp = l & 15;

  for (int s = 0; s < SEQL; ++s) {
    f32x4 acc0 = {0.f, 0.f, 0.f, 0.f}, acc1 = {0.f, 0.f, 0.f, 0.f};

    if (s) {
      // ---- poll + load A packets (this wave's 4 k-chunks), strip to LDS
      const unsigned expect = (unsigned)(s - 1);
      const ull* hb = hbuf8 + (size_t)((s - 1) & 1) * 32768;
      ull v[16];
      int gd = 0;
      bool ok;
      do {
#pragma unroll
        for (int it = 0; it < 4; ++it)
#pragma unroll
          for (int kk = 0; kk < 4; ++kk) {
            int row = it * 4 + c_row;
            int kb = gi * 4 + kk;
            v[it * 4 + kk] = __hip_atomic_load(
                hb + ((size_t)(dir * 64 + bg * 16 + row)) * 256 + kb * 16 + c_cp,
                __ATOMIC_RELAXED, __HIP_MEMORY_SCOPE_SYSTEM);
          }
        ok = true;
#pragma unroll
        for (int i = 0; i < 16; ++i) ok = ok && ((unsigned)(v[i] >> 32) == expect);
      } while (!__all(ok) && ++gd < (1 << 16));   // hang guard

#pragma unroll
      for (int it = 0; it < 4; ++it)
#pragma unroll
        for (int kk = 0; kk < 4; ++kk) {
          int row = it * 4 + c_row;
          int kb = gi * 4 + kk;
          int byte = (row * 1024 + kb * 64 + c_cp * 4) ^ ((row & 7) << 4);
          *(unsigned*)(As + byte) = (unsigned)v[it * 4 + kk];
        }
    }
    __syncthreads();   // A tile ready in LDS (or s==0: nothing, acc stays 0)

    if (s) {
#pragma unroll
      for (int kb = 0; kb < 16; ++kb) {
        int arow = l & 15;
        int abyte = (arow * 1024 + kb * 64 + (l >> 4) * 16) ^ ((arow & 7) << 4);
        short8 a = *(const short8*)(As + abyte);
        int kfrag = kb * 64 + (l >> 4) * 16;
        int kbyte = kfrag ^ ((l & 7) << 4);
        short8 b0 = *(const short8*)((const char*)lwh + gi * 32768 + (size_t)(l & 15) * 1024 + kbyte);
        short8 b1 = *(const short8*)((const char*)lwh + gi * 32768 + (size_t)(16 + (l & 15)) * 1024 + kbyte);
        acc0 = __builtin_amdgcn_mfma_f32_16x16x32_bf16(a, b0, acc0, 0, 0, 0);
        acc1 = __builtin_amdgcn_mfma_f32_16x16x32_bf16(a, b1, acc1, 0, 0, 0);
      }
    }

    {
      int col = l & 15, row0 = (l >> 4) * 4;
#pragma unroll
      for (int reg = 0; reg < 4; ++reg) {
        zbuf[gi][row0 + reg][col]      = acc0[reg];
        zbuf[gi][row0 + reg][col + 16] = acc1[reg];
      }
    }
    __syncthreads();   // zbuf handoff

    // gate math: thread owns (row r, cols 2q, 2q+1)
    float zi0 = zbuf[0][r][2 * q]     + bf2f((unsigned short)(zp[0] & 0xffffu));
    float zi1 = zbuf[0][r][2 * q + 1] + bf2f((unsigned short)(zp[0] >> 16));
    float zf0 = zbuf[1][r][2 * q]     + bf2f((unsigned short)(zp[1] & 0xffffu));
    float zf1 = zbuf[1][r][2 * q + 1] + bf2f((unsigned short)(zp[1] >> 16));
    float zo0 = zbuf[2][r][2 * q]     + bf2f((unsigned short)(zp[2] & 0xffffu));
    float zo1 = zbuf[2][r][2 * q + 1] + bf2f((unsigned short)(zp[2] >> 16));
    float zu0 = zbuf[3][r][2 * q]     + bf2f((unsigned short)(zp[3] & 0xffffu));
    float zu1 = zbuf[3][r][2 * q + 1] + bf2f((unsigned short)(zp[3] >> 16));

    c0 = sigm(zf0) * c0 + sigm(zi0) * tanh_f(zu0);
    h0 = sigm(zo0) * tanh_f(c0);
    c1 = sigm(zf1) * c1 + sigm(zi1) * tanh_f(zu1);
    h1 = sigm(zo1) * tanh_f(c1);

    // publish h packet: {2xbf16 exact, stamp = s} one 8B atomic store
    {
      unsigned hd = (unsigned)f2bf(h0) | ((unsigned)f2bf(h1) << 16);
      ull pv = (ull)hd | ((ull)(unsigned)s << 32);
      __hip_atomic_store(hbuf8 + (size_t)(s & 1) * 32768 + p_idx, pv,
                         __ATOMIC_RELAXED, __HIP_MEMORY_SCOPE_SYSTEM);
    }

    // off-critical-path: out store + next zpre prefetch
    {
      f32x2 ho; ho.x = h0; ho.y = h1;
      __builtin_nontemporal_store(ho, reinterpret_cast<f32x2*>(
          out + ((size_t)(bg * 16 + r) * SEQL + t) * 1024 + dir * 512 + hc0 + 2 * q));
    }
    if (s + 1 < SEQL) {
      t = dir ? (SEQL - 2 - s) : (s + 1);
      const char* zb = (const char*)zpre
          + (((size_t)t * 64 + bg * 16 + r) * ZDIM + hc0 + 2 * q) * 2;
#pragma unroll
      for (int gg = 0; gg < 4; ++gg) zp[gg] = *(const unsigned*)(zb + gg * 1024);
    }
  }

  // final states
  {
    size_t st = (size_t)(bg * 16 + r) * 1024 + dir * 512 + hc0 + 2 * q;
    f32x2 hv; hv.x = h0; hv.y = h1;
    f32x2 cv2; cv2.x = c0; cv2.y = c1;
    __builtin_nontemporal_store(hv, reinterpret_cast<f32x2*>(hstate + st));
    __builtin_nontemporal_store(cv2, reinterpret_cast<f32x2*>(cstate + st));
  }
}

// ---------------------------------------------------------------------- launch

extern "C" void kernel_launch(void* const* d_in, const int* in_sizes, int n_in,
                              void* d_out, int out_size, void* d_ws, size_t ws_size,
                              hipStream_t stream) {
  const float* x    = (const float*)d_in[0];
  const float* g    = (const float*)d_in[1];
  const float* W    = (const float*)d_in[2];
  const float* bias = (const float*)d_in[3];
  float* out = (float*)d_out;
  float* hstate = out + (size_t)16777216;            // 64*256*1024
  float* cstate = out + (size_t)16842752;            // + 64*1024

  char* ws = (char*)d_ws;
  ull* hbuf8 = (ull*)(ws + 0);                                // 512KB: 2 regions x [2][64][256] x 8B
  unsigned short* Xb   = (unsigned short*)(ws + 524288);      // 16MB
  unsigned short* Wt   = (unsigned short*)(ws + 17301504);    // 6MB
  unsigned short* gbf  = (unsigned short*)(ws + 23592960);    // 64KB
  float*          gbuf = (float*)(ws + 23658496);             // 512KB
  unsigned short* zpre = (unsigned short*)(ws + 24182784);    // 64MB

  // pre-stamp both h regions with 0xFF (matches no expected stamp; also cleans
  // previous replay's stamps -- harness doesn't re-poison ws between replays).
  hipMemsetAsync((void*)hbuf8, 0xFF, 524288, stream);

  k_prep<<<7184, 256, 0, stream>>>(x, g, W, Xb, gbf, Wt);
  k_gb<<<32, 256, 0, stream>>>(gbf, Wt, bias, gbuf);
  k_gemm_p1<<<dim3(128, 16), 256, 0, stream>>>(Xb, Wt, gbuf, zpre);
  k_rec<<<128, 256, 0, stream>>>(Wt, zpre, hbuf8, out, hstate, cstate);
}